// Round 6
// baseline (76.784 us; speedup 1.0000x reference)
//
#include <hip/hip_runtime.h>
#include <hip/hip_fp16.h>

typedef unsigned int u32;
typedef unsigned short u16;
typedef __attribute__((ext_vector_type(8))) _Float16 f16x8;
typedef __attribute__((ext_vector_type(4))) float f32x4;
typedef __attribute__((ext_vector_type(4))) u32 u32x4;

#define K_DIM 4096
#define N_DIM 14336
#define BM 64
#define BN 128
#define BK 64
#define NITER 32          // each of 2 K-parity sets handles 32 of the 64 K-steps
#define NBLK 448          // (256/64) * (14336/128)
#define LDA 72            // halfwords per A-row (144 B), bank-balanced

union U4F8 { u32x4 u; f16x8 v; };

// dequant one int32 (8 nibbles) -> f16x8 fragment in k-order [0,4,1,5,2,6,3,7]
// w = RN( RN(s*q) - z )  — bit-identical to the reference's f16 (s*q - z)
__device__ __forceinline__ f16x8 dq8(u32 q, __half2 s2, __half2 d2, __half2 z2) {
  U4F8 r;
  const u32 x0 = ( q        & 0x000F000Fu) | 0x64006400u;  // {1024+n0, 1024+n4}
  const u32 x1 = ((q >> 4)  & 0x000F000Fu) | 0x64006400u;  // {1024+n1, 1024+n5}
  const u32 x2 = ((q >> 8)  & 0x000F000Fu) | 0x64006400u;
  const u32 x3 = ((q >> 12) & 0x000F000Fu) | 0x64006400u;
  r.u.x = __builtin_bit_cast(u32, __hsub2(__hfma2(__builtin_bit_cast(__half2, x0), s2, d2), z2));
  r.u.y = __builtin_bit_cast(u32, __hsub2(__hfma2(__builtin_bit_cast(__half2, x1), s2, d2), z2));
  r.u.z = __builtin_bit_cast(u32, __hsub2(__hfma2(__builtin_bit_cast(__half2, x2), s2, d2), z2));
  r.u.w = __builtin_bit_cast(u32, __hsub2(__hfma2(__builtin_bit_cast(__half2, x3), s2, d2), z2));
  return r.v;
}

__device__ __forceinline__ u32 pkrtz(float a, float b) {  // exact: x was f16
  return __builtin_bit_cast(u32, __builtin_amdgcn_cvt_pkrtz(a, b));
}

__global__ __launch_bounds__(512, 4) void kivi_gemm(
    const float* __restrict__ X,    // x upconverted to f32 [256][4096]
    const int* __restrict__ QW,     // [512][14336]; nibble j of row r -> k = r*8+j
    const float* __restrict__ S,    // [32][14336]
    const float* __restrict__ Z,    // [32][14336]
    float* __restrict__ O)          // out f32 [256][14336]
{
  // A tiles only: [set][buf][row][LDA]; epilogue reuses as float [64][132]
  __shared__ __align__(16) u16 As[2][2][BM][LDA];   // 36,864 B

  const int tid  = threadIdx.x;
  const int lane = tid & 63;
  const int w    = tid >> 6;
  const int ws   = w >> 2;          // K-parity set: t = 2*i + ws
  const int wl   = w & 3;
  const int stid = tid & 255;

  // XCD-aware bijective swizzle: 448 = 8*56; m-tile minor so same-XCD shares QW panel
  const int b  = blockIdx.x;
  const int L  = (b & 7) * 56 + (b >> 3);
  const int m0 = (L & 3) * BM;
  const int n0 = (L >> 2) * BN;

  // compute geometry: wave-tile 32x64; frags 2m x 4n, 2 k-slices
  const int wm = wl >> 1, wn = wl & 1;
  const int mb = wm * 32, nb = wn * 64;
  const int fr = lane & 15, fq = lane >> 4;
  const int cb = n0 + nb + fr;      // B col for ni=0

  // A staging: thread stid -> row stid>>2, 16 f32 at col (stid&3)*16
  const int arow = stid >> 2;
  const int acol = (stid & 3) * 16;

  f32x4 acc[2][4];
#pragma unroll
  for (int mi = 0; mi < 2; ++mi)
#pragma unroll
    for (int ni = 0; ni < 4; ++ni)
      acc[mi][ni] = (f32x4){0.f, 0.f, 0.f, 0.f};

  f32x4 aReg[4];
  u32 qReg[2][4];
  float sv[4], zv[4];

  auto loadAx = [&](int t) {
    const float* p = X + (size_t)(m0 + arow) * K_DIM + t * BK + acol;
    aReg[0] = *(const f32x4*)(p);
    aReg[1] = *(const f32x4*)(p + 4);
    aReg[2] = *(const f32x4*)(p + 8);
    aReg[3] = *(const f32x4*)(p + 12);
  };
  // sigma-pack (pairs (j, j+4)) to match dq8's k-order, then 2x b128 writes
  auto writeAx = [&](int buf) {
#pragma unroll
    for (int c = 0; c < 2; ++c) {
      u32x4 pk;
      pk.x = pkrtz(aReg[c * 2][0], aReg[c * 2 + 1][0]);
      pk.y = pkrtz(aReg[c * 2][1], aReg[c * 2 + 1][1]);
      pk.z = pkrtz(aReg[c * 2][2], aReg[c * 2 + 1][2]);
      pk.w = pkrtz(aReg[c * 2][3], aReg[c * 2 + 1][3]);
      *(u32x4*)&As[ws][buf][arow][acol + c * 8] = pk;
    }
  };
  auto loadBq = [&](int t, int g) {
    const size_t rbase = (size_t)(t * 8 + fq) * N_DIM + cb;
#pragma unroll
    for (int ks = 0; ks < 2; ++ks)
#pragma unroll
      for (int ni = 0; ni < 4; ++ni)
        qReg[ks][ni] = *(const u32*)(QW + rbase + (size_t)ks * 4 * N_DIM + ni * 16);
#pragma unroll
    for (int ni = 0; ni < 4; ++ni) {
      sv[ni] = S[(size_t)g * N_DIM + cb + ni * 16];
      zv[ni] = Z[(size_t)g * N_DIM + cb + ni * 16];
    }
  };

  // prologue: stage K-step t=ws into buf 0; B ints for t=ws in regs
  loadAx(ws);
  loadBq(ws, 0);
  writeAx(0);
  __syncthreads();

  const __half hneg1024 = __float2half(-1024.f);

  for (int i = 0; i < NITER; ++i) {
    const int t   = 2 * i + ws;
    const int cur = i & 1;
    const bool pf = (i + 1 < NITER);

    if (pf) loadAx(t + 2);          // issue A globals early (covered by compute)

    // per-group dequant constants (group g = i; changes every iteration)
    __half2 s2[4], d2[4], z2[4];
#pragma unroll
    for (int ni = 0; ni < 4; ++ni) {
      const __half sh = __float2half(sv[ni]);   // matches ref astype(f16)
      const __half zh = __float2half(zv[ni]);
      const __half dh = __hmul(sh, hneg1024);   // exact (exponent shift)
      s2[ni] = __halves2half2(sh, sh);
      d2[ni] = __halves2half2(dh, dh);
      z2[ni] = __halves2half2(zh, zh);
    }

#pragma unroll
    for (int ks = 0; ks < 2; ++ks) {
      f16x8 af[2], bf[4];
#pragma unroll
      for (int mi = 0; mi < 2; ++mi)
        af[mi] = *(const f16x8*)&As[ws][cur][mb + mi * 16 + fr][ks * 32 + fq * 8];
#pragma unroll
      for (int ni = 0; ni < 4; ++ni)
        bf[ni] = dq8(qReg[ks][ni], s2[ni], d2[ni], z2[ni]);
#pragma unroll
      for (int mi = 0; mi < 2; ++mi)
#pragma unroll
        for (int ni = 0; ni < 4; ++ni)
          acc[mi][ni] = __builtin_amdgcn_mfma_f32_16x16x32_f16(
              af[mi], bf[ni], acc[mi][ni], 0, 0, 0);
    }

    if (pf) {
      writeAx(cur ^ 1);             // pack (waits vmcnt) + write t+2 to other buf
      loadBq(t + 2, i + 1);         // issue B ints + scales for next iter
    }
    __syncthreads();                // publishes writes; ends reads of buf[cur]
  }

  // cross-set reduction: set 1 -> LDS (f32 [64][132]), set 0 adds + stores
  float (*Lr)[132] = reinterpret_cast<float(*)[132]>(&As[0][0][0][0]);  // 33,792 B
  if (ws == 1) {
#pragma unroll
    for (int mi = 0; mi < 2; ++mi)
#pragma unroll
      for (int ni = 0; ni < 4; ++ni)
#pragma unroll
        for (int r = 0; r < 4; ++r)
          Lr[mb + mi * 16 + fq * 4 + r][nb + ni * 16 + fr] = acc[mi][ni][r];
  }
  __syncthreads();
  if (ws == 0) {
#pragma unroll
    for (int mi = 0; mi < 2; ++mi)
#pragma unroll
      for (int ni = 0; ni < 4; ++ni)
#pragma unroll
        for (int r = 0; r < 4; ++r) {
          const int row = mb + mi * 16 + fq * 4 + r;
          const int col = nb + ni * 16 + fr;
          O[(size_t)(m0 + row) * N_DIM + n0 + col] = acc[mi][ni][r] + Lr[row][col];
        }
  }
}

extern "C" void kernel_launch(void* const* d_in, const int* in_sizes, int n_in,
                              void* d_out, int out_size, void* d_ws, size_t ws_size,
                              hipStream_t stream) {
  const float* X  = (const float*)d_in[0];
  const int*   QW = (const int*)d_in[1];
  const float* S  = (const float*)d_in[2];
  const float* Zp = (const float*)d_in[3];
  float* O = (float*)d_out;
  hipLaunchKernelGGL(kivi_gemm, dim3(NBLK), dim3(512), 0, stream, X, QW, S, Zp, O);
}